// Round 12
// baseline (307.575 us; speedup 1.0000x reference)
//
#include <hip/hip_runtime.h>

typedef unsigned short u16;
typedef unsigned int u32;
typedef __bf16 bf16x8 __attribute__((ext_vector_type(8)));
typedef float f32x4 __attribute__((ext_vector_type(4)));
typedef u16 u16x8 __attribute__((ext_vector_type(8)));

__device__ __forceinline__ u16 f2bf(float f) {
    union { float f; u32 i; } v; v.f = f;
    u32 x = v.i;
    u32 r = (x + 0x7fffu + ((x >> 16) & 1u)) >> 16;
    return (u16)r;
}
__device__ __forceinline__ float bf2f(u16 u) {
    union { u32 i; float f; } v; v.i = ((u32)u) << 16; return v.f;
}
__device__ __forceinline__ u16 f2h(float f) {
    union { _Float16 h; u16 u; } v; v.h = (_Float16)f; return v.u;
}
__device__ __forceinline__ float h2f(u16 u) {
    union { _Float16 h; u16 u; } v; v.u = u; return (float)v.h;
}

// async global->LDS, 16B per lane. LDS dest must be lane-linear per wave.
__device__ __forceinline__ void gld16(const void* g, void* l) {
    __builtin_amdgcn_global_load_lds(
        (const __attribute__((address_space(1))) void*)g,
        (__attribute__((address_space(3))) void*)l, 16, 0, 0);
}

// -------- prep: LN1 (blocks 0..8191) + weight transpose (blocks 8192+) ----
// LN1 first so the long pole starts dispatching immediately.
__global__ __launch_bounds__(256) void prep(
    const float* __restrict__ x, const float* __restrict__ g,
    const float* __restrict__ b, u16* __restrict__ y,
    const float* __restrict__ w0, const float* __restrict__ w1,
    const float* __restrict__ w2, const float* __restrict__ w3,
    u16* __restrict__ d0, u16* __restrict__ d1,
    u16* __restrict__ d2, u16* __restrict__ d3)
{
    __shared__ u16 tl[32][33];
    if (blockIdx.x >= 8192) {
        int bx = blockIdx.x - 8192;
        int mat = bx >> 8;          // 0..3
        int tile = bx & 255;        // 16x16 tiles of 32x32
        int tx = (tile & 15) * 32;
        int ty = (tile >> 4) * 32;
        const float* src = (mat == 0) ? w0 : (mat == 1) ? w1 : (mat == 2) ? w2 : w3;
        u16* dst = (mat == 0) ? d0 : (mat == 1) ? d1 : (mat == 2) ? d2 : d3;
        int col = threadIdx.x & 31;
        int r8  = threadIdx.x >> 5;   // 0..7
        #pragma unroll
        for (int k = 0; k < 4; ++k) {
            int rr = r8 + k * 8;
            tl[rr][col] = f2bf(src[(ty + rr) * 512 + tx + col]);
        }
        __syncthreads();
        #pragma unroll
        for (int k = 0; k < 4; ++k) {
            int rr = r8 + k * 8;
            dst[(tx + rr) * 512 + ty + col] = tl[col][rr];
        }
        return;
    }
    int gid = blockIdx.x * 256 + threadIdx.x;
    int row = gid >> 6;
    int lane = gid & 63;

    const float* xr = x + (size_t)row * 512 + lane * 8;
    float4 a0 = *(const float4*)xr;
    float4 a1 = *(const float4*)(xr + 4);
    float f[8] = {a0.x, a0.y, a0.z, a0.w, a1.x, a1.y, a1.z, a1.w};
    float sm = 0.f, sm2 = 0.f;
    #pragma unroll
    for (int e = 0; e < 8; ++e) { sm += f[e]; sm2 += f[e] * f[e]; }
    #pragma unroll
    for (int o = 32; o > 0; o >>= 1) { sm += __shfl_xor(sm, o); sm2 += __shfl_xor(sm2, o); }
    const float inv = 1.0f / 512.0f;
    float mean = sm * inv;
    float var  = sm2 * inv - mean * mean;
    float rstd = rsqrtf(var + 1e-5f);

    float4 g0 = *(const float4*)(g + lane * 8);
    float4 g1 = *(const float4*)(g + lane * 8 + 4);
    float4 b0 = *(const float4*)(b + lane * 8);
    float4 b1 = *(const float4*)(b + lane * 8 + 4);
    float gg[8] = {g0.x, g0.y, g0.z, g0.w, g1.x, g1.y, g1.z, g1.w};
    float bb[8] = {b0.x, b0.y, b0.z, b0.w, b1.x, b1.y, b1.z, b1.w};
    u16x8 ov;
    #pragma unroll
    for (int e = 0; e < 8; ++e)
        ov[e] = f2bf((f[e] - mean) * rstd * gg[e] + bb[e]);
    *(u16x8*)(y + (size_t)row * 512 + lane * 8) = ov;
}

// -------- LayerNorm over H=512: fp32 in -> bf16 out (used for LN2) --------
__global__ __launch_bounds__(256) void ln_k(
    const float* __restrict__ x, const float* __restrict__ g,
    const float* __restrict__ b, u16* __restrict__ y, int rows)
{
    int gid = blockIdx.x * blockDim.x + threadIdx.x;
    int row = gid >> 6;
    int lane = gid & 63;
    if (row >= rows) return;

    const float* xr = x + (size_t)row * 512 + lane * 8;
    float4 a0 = *(const float4*)xr;
    float4 a1 = *(const float4*)(xr + 4);
    float f[8] = {a0.x, a0.y, a0.z, a0.w, a1.x, a1.y, a1.z, a1.w};
    float sm = 0.f, sm2 = 0.f;
    #pragma unroll
    for (int e = 0; e < 8; ++e) { sm += f[e]; sm2 += f[e] * f[e]; }
    #pragma unroll
    for (int o = 32; o > 0; o >>= 1) { sm += __shfl_xor(sm, o); sm2 += __shfl_xor(sm2, o); }
    const float inv = 1.0f / 512.0f;
    float mean = sm * inv;
    float var  = sm2 * inv - mean * mean;
    float rstd = rsqrtf(var + 1e-5f);

    float4 g0 = *(const float4*)(g + lane * 8);
    float4 g1 = *(const float4*)(g + lane * 8 + 4);
    float4 b0 = *(const float4*)(b + lane * 8);
    float4 b1 = *(const float4*)(b + lane * 8 + 4);
    float gg[8] = {g0.x, g0.y, g0.z, g0.w, g1.x, g1.y, g1.z, g1.w};
    float bb[8] = {b0.x, b0.y, b0.z, b0.w, b1.x, b1.y, b1.z, b1.w};
    u16x8 ov;
    #pragma unroll
    for (int e = 0; e < 8; ++e)
        ov[e] = f2bf((f[e] - mean) * rstd * gg[e] + bb[e]);
    *(u16x8*)(y + (size_t)row * 512 + lane * 8) = ov;
}

// -------- gate GEMM: 128x128 tile, dual-B, dbuf prefetch ------------------
// launch_bounds(256,2): the 2-block/CU PROVEN config. Do NOT raise: the
// kernel's live state (~190 VGPR incl. 128 acc) spills at 3 blocks/CU
// (round-10: VGPR 84, FETCH/WRITE inflated, 54->95us).
// Chunk length 16: each 16-row i-block is one scan chunk; the fold needs
// only the 4-row segment + 2-step ordered quad combine (no pair merge).
__global__ __launch_bounds__(256, 2) void gemm_gate(
    const u16* __restrict__ A, const u16* __restrict__ Bt0,
    const u16* __restrict__ Bt1, const float* __restrict__ bias0,
    const float* __restrict__ bias1, u32* __restrict__ cvb,
    float* __restrict__ chCp, float* __restrict__ chVp)
{
    constexpr int Kd = 512, Nd = 512;
    constexpr int BUF = 12288;
    __shared__ __align__(16) u16 smem[2 * BUF];   // 48 KiB

    int bx = blockIdx.x;
    bx = (bx & 7) * 128 + (bx >> 3);     // XCD-contiguous (1024%8==0)
    int m0 = (bx >> 2) * 128;
    int n0 = (bx & 3) * 128;
    int tid = threadIdx.x;
    int lane = tid & 63;
    int w = tid >> 6;
    int wm = w & 1, wn = w >> 1;
    int l16 = lane & 15;
    int quad = lane >> 4;

    f32x4 acc0[4][4] = {};
    f32x4 acc1[4][4] = {};

    int ch0 = tid, ch1 = tid + 256;
    int row0 = ch0 >> 2, row1 = ch1 >> 2;
    int g0 = (ch0 & 3) ^ ((ch0 >> 3) & 3);
    int g1 = (ch1 & 3) ^ ((ch1 >> 3) & 3);
    const u16* a0p  = A   + (size_t)(m0 + row0) * Kd + g0 * 8;
    const u16* a1p  = A   + (size_t)(m0 + row1) * Kd + g1 * 8;
    const u16* b00p = Bt0 + (size_t)(n0 + row0) * Kd + g0 * 8;
    const u16* b01p = Bt0 + (size_t)(n0 + row1) * Kd + g1 * 8;
    const u16* b10p = Bt1 + (size_t)(n0 + row0) * Kd + g0 * 8;
    const u16* b11p = Bt1 + (size_t)(n0 + row1) * Kd + g1 * 8;

#define STAGE(sl, kt) { \
    int k0_ = (kt) * 32; \
    u16* L_ = smem + (sl) * BUF; \
    gld16(a0p  + k0_, &L_[ch0 * 8]); \
    gld16(a1p  + k0_, &L_[ch1 * 8]); \
    gld16(b00p + k0_, &L_[4096 + ch0 * 8]); \
    gld16(b01p + k0_, &L_[4096 + ch1 * 8]); \
    gld16(b10p + k0_, &L_[8192 + ch0 * 8]); \
    gld16(b11p + k0_, &L_[8192 + ch1 * 8]); }

    STAGE(0, 0);
    __syncthreads();

    for (int kt = 0; kt < Kd / 32; ++kt) {
        int cur = kt & 1;
        if (kt < Kd / 32 - 1) STAGE(cur ^ 1, kt + 1);

        const u16* As  = smem + cur * BUF;
        const u16* Bs0 = As + 4096;
        const u16* Bs1 = As + 8192;
        bf16x8 af[4], bf0[4], bf1[4];
        #pragma unroll
        for (int i = 0; i < 4; ++i) {
            int ra = wm * 64 + i * 16 + l16;
            int rb = wn * 64 + i * 16 + l16;
            int ga = quad ^ ((ra >> 1) & 3);
            int gb = quad ^ ((rb >> 1) & 3);
            af[i]  = *(const bf16x8*)&As [ra * 32 + ga * 8];
            bf0[i] = *(const bf16x8*)&Bs0[rb * 32 + gb * 8];
            bf1[i] = *(const bf16x8*)&Bs1[rb * 32 + gb * 8];
        }
        #pragma unroll
        for (int i = 0; i < 4; ++i)
            #pragma unroll
            for (int j = 0; j < 4; ++j) {
                acc0[i][j] = __builtin_amdgcn_mfma_f32_16x16x32_bf16(af[i], bf0[j], acc0[i][j], 0, 0, 0);
                acc1[i][j] = __builtin_amdgcn_mfma_f32_16x16x32_bf16(af[i], bf1[j], acc1[i][j], 0, 0, 0);
            }
        __syncthreads();
    }
#undef STAGE

    // gate epilogue + per-16-row-chunk (C,V) fold, all in registers
    #pragma unroll
    for (int j = 0; j < 4; ++j) {
        int col = n0 + wn * 64 + j * 16 + l16;
        float bk  = bias0[col];
        float bh2 = bias1[col];
        #pragma unroll
        for (int i = 0; i < 4; ++i) {
            int grow = m0 + wm * 64 + i * 16;    // chunk base row
            float C = 1.f, V = 0.f;
            #pragma unroll
            for (int r = 0; r < 4; ++r) {
                int row = grow + quad * 4 + r;
                float kk = acc0[i][j][r] + bk;
                float hh = acc1[i][j][r] + bh2;
                float z = __builtin_amdgcn_rcpf(1.f + __expf(-kk));
                float c = 1.f - z;
                float gs = __builtin_amdgcn_rcpf(1.f + __expf(-hh));
                float gg = (hh >= 0.f) ? (hh + 0.5f) : gs;
                float v = z * gg;
                cvb[(size_t)row * Nd + col] =
                    (u32)f2h(c) | ((u32)f2h(v) << 16);
                C *= c;
                V = fmaf(c, V, v);
            }
            // ordered cross-quad combine: quad q holds rows q*4..q*4+3.
            // combine(later L, earlier E): C = CE*CL ; V = CL*VE + VL
            float oc = __shfl_xor(C, 16), ov = __shfl_xor(V, 16);
            V = (quad & 1) ? fmaf(C, ov, V) : fmaf(oc, V, ov);
            C *= oc;
            oc = __shfl_xor(C, 32); ov = __shfl_xor(V, 32);
            V = (quad & 2) ? fmaf(C, ov, V) : fmaf(oc, V, ov);
            C *= oc;
            if (quad == 0) {
                int bb_  = grow >> 13;               // batch (8192 rows)
                int chgl = (grow & 8191) >> 4;       // chunk 0..511
                int idx = chgl * 2048 + bb_ * 512 + col;
                chCp[idx] = C;
                chVp[idx] = V;
            }
        }
    }
}

// -------- FFN GEMM: 128x128 tile, single-B, dbuf prefetch -----------------
// launch_bounds(256,3): acc is only 64 VGPR here (~130 live total < 170
// budget at 3 blocks/CU) -> register-safe occupancy bump. LDS 32K x3 = 96K.
// MODE 1: out = relu(A@B + bias) (bf16). MODE 2: out = A@B + bias + resid
// (fp32; same-thread alias-safe).
template <int MODE>
__global__ __launch_bounds__(256, 3) void gemm_bt(
    const u16* __restrict__ A, const u16* __restrict__ Bt0,
    const float* __restrict__ bias0, const float* __restrict__ resid,
    void* __restrict__ out0v)
{
    constexpr int Kd = 512, Nd = 512;
    constexpr int BUF = 8192;
    __shared__ __align__(16) u16 smem[2 * BUF];   // 32 KiB

    int bx = blockIdx.x;
    bx = (bx & 7) * 128 + (bx >> 3);
    int m0 = (bx >> 2) * 128;
    int n0 = (bx & 3) * 128;
    int tid = threadIdx.x;
    int lane = tid & 63;
    int w = tid >> 6;
    int wm = w & 1, wn = w >> 1;
    int l16 = lane & 15;
    int quad = lane >> 4;

    f32x4 acc0[4][4] = {};

    int ch0 = tid, ch1 = tid + 256;
    int row0 = ch0 >> 2, row1 = ch1 >> 2;
    int g0 = (ch0 & 3) ^ ((ch0 >> 3) & 3);
    int g1 = (ch1 & 3) ^ ((ch1 >> 3) & 3);
    const u16* a0p  = A   + (size_t)(m0 + row0) * Kd + g0 * 8;
    const u16* a1p  = A   + (size_t)(m0 + row1) * Kd + g1 * 8;
    const u16* b00p = Bt0 + (size_t)(n0 + row0) * Kd + g0 * 8;
    const u16* b01p = Bt0 + (size_t)(n0 + row1) * Kd + g1 * 8;

#define STAGE(sl, kt) { \
    int k0_ = (kt) * 32; \
    u16* L_ = smem + (sl) * BUF; \
    gld16(a0p  + k0_, &L_[ch0 * 8]); \
    gld16(a1p  + k0_, &L_[ch1 * 8]); \
    gld16(b00p + k0_, &L_[4096 + ch0 * 8]); \
    gld16(b01p + k0_, &L_[4096 + ch1 * 8]); }

    STAGE(0, 0);
    __syncthreads();

    for (int kt = 0; kt < Kd / 32; ++kt) {
        int cur = kt & 1;
        if (kt < Kd / 32 - 1) STAGE(cur ^ 1, kt + 1);

        const u16* As  = smem + cur * BUF;
        const u16* Bs0 = As + 4096;
        bf16x8 af[4], bf0[4];
        #pragma unroll
        for (int i = 0; i < 4; ++i) {
            int ra = wm * 64 + i * 16 + l16;
            int rb = wn * 64 + i * 16 + l16;
            int ga = quad ^ ((ra >> 1) & 3);
            int gb = quad ^ ((rb >> 1) & 3);
            af[i]  = *(const bf16x8*)&As [ra * 32 + ga * 8];
            bf0[i] = *(const bf16x8*)&Bs0[rb * 32 + gb * 8];
        }
        #pragma unroll
        for (int i = 0; i < 4; ++i)
            #pragma unroll
            for (int j = 0; j < 4; ++j)
                acc0[i][j] = __builtin_amdgcn_mfma_f32_16x16x32_bf16(af[i], bf0[j], acc0[i][j], 0, 0, 0);
        __syncthreads();
    }
#undef STAGE

    #pragma unroll
    for (int j = 0; j < 4; ++j) {
        int col = n0 + wn * 64 + j * 16 + l16;
        float b0 = bias0[col];
        #pragma unroll
        for (int i = 0; i < 4; ++i) {
            #pragma unroll
            for (int r = 0; r < 4; ++r) {
                int row = m0 + wm * 64 + i * 16 + quad * 4 + r;
                size_t off = (size_t)row * Nd + col;
                float v0 = acc0[i][j][r] + b0;
                if (MODE == 1) {
                    ((u16*)out0v)[off] = f2bf(fmaxf(v0, 0.f));
                } else {
                    ((float*)out0v)[off] = v0 + resid[off];
                }
            }
        }
    }
}

// -------- fused chunk-state scan (512 chunks of 16) ------------------------
// Block group sc (0..15) covers chunks sc*32..sc*32+31; redundantly
// composes the prefix (coalesced streaming reads, L2/L3-resident 8 MiB),
// then replays its 32 chunks writing hst.
__global__ __launch_bounds__(256) void scanB(
    const float* __restrict__ chC, const float* __restrict__ chV,
    float* __restrict__ hst)
{
    int bx = blockIdx.x;                 // 128 blocks
    int sc = bx >> 3;                    // 0..15
    int s  = (bx & 7) * 256 + threadIdx.x;   // 0..2047
    float h = 0.5f;
    int pre = sc * 32;
    #pragma unroll 8
    for (int c = 0; c < pre; ++c)
        h = fmaf(chC[c * 2048 + s], h, chV[c * 2048 + s]);
    #pragma unroll
    for (int i = 0; i < 32; ++i) {
        int ch = sc * 32 + i;
        hst[ch * 2048 + s] = h;
        h = fmaf(chC[ch * 2048 + s], h, chV[ch * 2048 + s]);
    }
}

// Pass C: replay 16-chunk from packed fp16 gates; x2 = x + h.
// 2048 blocks x 256 thr = 8192 waves = 100% occupancy; 16 iterations.
__global__ __launch_bounds__(256) void scanC(
    const u32* __restrict__ cv, const float* __restrict__ hst,
    const float* __restrict__ x, float* __restrict__ x2)
{
    int gid = blockIdx.x * 256 + threadIdx.x;   // 524288 threads
    int h2 = (gid & 255) * 2;
    int rest = gid >> 8;
    int b = rest & 3;
    int ch = rest >> 2;                          // 0..511
    size_t base = ((size_t)(b * 8192 + ch * 16)) * 512 + h2;
    int sidx = ch * 2048 + b * 512 + h2;
    float h0 = hst[sidx], h1 = hst[sidx + 1];
    #pragma unroll
    for (int t = 0; t < 16; ++t) {
        size_t off = base + (size_t)t * 512;
        uint2 g2 = *(const uint2*)(cv + off);
        float2 xx = *(const float2*)(x + off);
        h0 = fmaf(h2f((u16)(g2.x & 0xffffu)), h0, h2f((u16)(g2.x >> 16)));
        h1 = fmaf(h2f((u16)(g2.y & 0xffffu)), h1, h2f((u16)(g2.y >> 16)));
        float2 o; o.x = xx.x + h0; o.y = xx.y + h1;
        *(float2*)(x2 + off) = o;
    }
}

// ---------------------------------------------------------------------------
// All I/O fp32 (per reference). Internals bf16 (GEMM) / fp16 (gates).
// 7 dispatches: prep, gemm_gate, scanB, scanC, ln_k, gemm_bt<1>, gemm_bt<2>.
// ws layout (99.5 MiB):
//   wt  @ 0      : 2 MiB   (4 transposed bf16 weights)
//   a   @ 3.5 MiB: 32 MiB  bf16. LN1-out -> hst (4M) -> LN2-out.
//   cv  @ 35.5 M : 64 MiB  u32 packed (c,v) gates -> first 32 MiB reused
//     as FFN hidden after scanC.
// chC/chV (4 MiB each) alias d_out (dead until scanC; consumed by scanB
// before scanC overwrites d_out with x2).
// d_out holds x2 after scanC, then the final output (gemm_bt<2> reads
// resid[off] then writes out[off] from the same thread).
extern "C" void kernel_launch(void* const* d_in, const int* in_sizes, int n_in,
                              void* d_out, int out_size, void* d_ws, size_t ws_size,
                              hipStream_t stream)
{
    const float* x    = (const float*)d_in[0];
    const float* ln1g = (const float*)d_in[1];
    const float* ln1b = (const float*)d_in[2];
    const float* Wz   = (const float*)d_in[3];
    const float* bz   = (const float*)d_in[4];
    const float* Wh   = (const float*)d_in[5];
    const float* bh   = (const float*)d_in[6];
    const float* ln2g = (const float*)d_in[7];
    const float* ln2b = (const float*)d_in[8];
    const float* W1   = (const float*)d_in[9];
    const float* b1   = (const float*)d_in[10];
    const float* W2   = (const float*)d_in[11];
    const float* b2   = (const float*)d_in[12];
    float* out = (float*)d_out;

    char* ws = (char*)d_ws;
    constexpr size_t MB = 1024 * 1024;
    u16* Wzt = (u16*)(ws);
    u16* Wht = Wzt + 262144;
    u16* W1t = Wzt + 524288;
    u16* W2t = Wzt + 786432;
    u16* a   = (u16*)(ws + 3 * MB + 512 * 1024);   // LN1 out / LN2 out
    u32* cv  = (u32*)(ws + 35 * MB + 512 * 1024);  // packed gates (64 MiB)
    u16* hid = (u16*)(ws + 35 * MB + 512 * 1024);  // FFN hidden (reuses cv)
    float* hst = (float*)(ws + 3 * MB + 512 * 1024);   // 4 MiB, aliases a
    float* chC = (float*)d_out;
    float* chV = chC + 1048576;          // +4 MiB

    // a = bf16(LN1(x)) ; weights transposed to bf16
    prep<<<9216, 256, 0, stream>>>(x, ln1g, ln1b, a,
                                   Wz, Wh, W1, W2, Wzt, Wht, W1t, W2t);
    // cv = packed fp16 gates of (a@Wz+bz, a@Wh+bh); chC/chV = chunk states
    gemm_gate<<<1024, 256, 0, stream>>>(a, Wzt, Wht, bz, bh, cv, chC, chV);
    // hst = per-chunk start states (single fused pass)
    scanB<<<128, 256, 0, stream>>>(chC, chV, hst);
    // d_out = x + h  (fp32 residual stream; overwrites chC/chV - consumed)
    scanC<<<2048, 256, 0, stream>>>(cv, hst, x, out);
    // a = bf16(LN2(d_out))  (hst region dead)
    ln_k<<<8192, 256, 0, stream>>>(out, ln2g, ln2b, a, 32768);
    // hid = relu(a @ W1 + b1)  (bf16; cv region dead)
    gemm_bt<1><<<1024, 256, 0, stream>>>(a, W1t, b1, nullptr, hid);
    // d_out = hid @ W2 + b2 + d_out  (fp32)
    gemm_bt<2><<<1024, 256, 0, stream>>>(hid, W2t, b2, out, out);
}

// Round 13
// 298.952 us; speedup vs baseline: 1.0288x; 1.0288x over previous
//
#include <hip/hip_runtime.h>

typedef unsigned short u16;
typedef unsigned int u32;
typedef __bf16 bf16x8 __attribute__((ext_vector_type(8)));
typedef float f32x4 __attribute__((ext_vector_type(4)));
typedef u16 u16x8 __attribute__((ext_vector_type(8)));

__device__ __forceinline__ u16 f2bf(float f) {
    union { float f; u32 i; } v; v.f = f;
    u32 x = v.i;
    u32 r = (x + 0x7fffu + ((x >> 16) & 1u)) >> 16;
    return (u16)r;
}
__device__ __forceinline__ float bf2f(u16 u) {
    union { u32 i; float f; } v; v.i = ((u32)u) << 16; return v.f;
}
__device__ __forceinline__ u16 f2h(float f) {
    union { _Float16 h; u16 u; } v; v.h = (_Float16)f; return v.u;
}
__device__ __forceinline__ float h2f(u16 u) {
    union { _Float16 h; u16 u; } v; v.u = u; return (float)v.h;
}

// async global->LDS, 16B per lane. LDS dest must be lane-linear per wave.
__device__ __forceinline__ void gld16(const void* g, void* l) {
    __builtin_amdgcn_global_load_lds(
        (const __attribute__((address_space(1))) void*)g,
        (__attribute__((address_space(3))) void*)l, 16, 0, 0);
}

// -------- prep: weight transpose (blocks 0..1023) + LN1 (blocks 1024+) ----
__global__ __launch_bounds__(256) void prep(
    const float* __restrict__ x, const float* __restrict__ g,
    const float* __restrict__ b, u16* __restrict__ y,
    const float* __restrict__ w0, const float* __restrict__ w1,
    const float* __restrict__ w2, const float* __restrict__ w3,
    u16* __restrict__ d0, u16* __restrict__ d1,
    u16* __restrict__ d2, u16* __restrict__ d3)
{
    __shared__ u16 tl[32][33];
    if (blockIdx.x < 1024) {
        int bx = blockIdx.x;
        int mat = bx >> 8;          // 0..3
        int tile = bx & 255;        // 16x16 tiles of 32x32
        int tx = (tile & 15) * 32;
        int ty = (tile >> 4) * 32;
        const float* src = (mat == 0) ? w0 : (mat == 1) ? w1 : (mat == 2) ? w2 : w3;
        u16* dst = (mat == 0) ? d0 : (mat == 1) ? d1 : (mat == 2) ? d2 : d3;
        int col = threadIdx.x & 31;
        int r8  = threadIdx.x >> 5;   // 0..7
        #pragma unroll
        for (int k = 0; k < 4; ++k) {
            int rr = r8 + k * 8;
            tl[rr][col] = f2bf(src[(ty + rr) * 512 + tx + col]);
        }
        __syncthreads();
        #pragma unroll
        for (int k = 0; k < 4; ++k) {
            int rr = r8 + k * 8;
            dst[(tx + rr) * 512 + ty + col] = tl[col][rr];
        }
        return;
    }
    int gid = (blockIdx.x - 1024) * 256 + threadIdx.x;
    int row = gid >> 6;
    int lane = gid & 63;

    const float* xr = x + (size_t)row * 512 + lane * 8;
    float4 a0 = *(const float4*)xr;
    float4 a1 = *(const float4*)(xr + 4);
    float f[8] = {a0.x, a0.y, a0.z, a0.w, a1.x, a1.y, a1.z, a1.w};
    float sm = 0.f, sm2 = 0.f;
    #pragma unroll
    for (int e = 0; e < 8; ++e) { sm += f[e]; sm2 += f[e] * f[e]; }
    #pragma unroll
    for (int o = 32; o > 0; o >>= 1) { sm += __shfl_xor(sm, o); sm2 += __shfl_xor(sm2, o); }
    const float inv = 1.0f / 512.0f;
    float mean = sm * inv;
    float var  = sm2 * inv - mean * mean;
    float rstd = rsqrtf(var + 1e-5f);

    float4 g0 = *(const float4*)(g + lane * 8);
    float4 g1 = *(const float4*)(g + lane * 8 + 4);
    float4 b0 = *(const float4*)(b + lane * 8);
    float4 b1 = *(const float4*)(b + lane * 8 + 4);
    float gg[8] = {g0.x, g0.y, g0.z, g0.w, g1.x, g1.y, g1.z, g1.w};
    float bb[8] = {b0.x, b0.y, b0.z, b0.w, b1.x, b1.y, b1.z, b1.w};
    u16x8 ov;
    #pragma unroll
    for (int e = 0; e < 8; ++e)
        ov[e] = f2bf((f[e] - mean) * rstd * gg[e] + bb[e]);
    *(u16x8*)(y + (size_t)row * 512 + lane * 8) = ov;
}

// -------- LayerNorm over H=512: fp32 in -> bf16 out (used for LN2) --------
__global__ __launch_bounds__(256) void ln_k(
    const float* __restrict__ x, const float* __restrict__ g,
    const float* __restrict__ b, u16* __restrict__ y, int rows)
{
    int gid = blockIdx.x * blockDim.x + threadIdx.x;
    int row = gid >> 6;
    int lane = gid & 63;
    if (row >= rows) return;

    const float* xr = x + (size_t)row * 512 + lane * 8;
    float4 a0 = *(const float4*)xr;
    float4 a1 = *(const float4*)(xr + 4);
    float f[8] = {a0.x, a0.y, a0.z, a0.w, a1.x, a1.y, a1.z, a1.w};
    float sm = 0.f, sm2 = 0.f;
    #pragma unroll
    for (int e = 0; e < 8; ++e) { sm += f[e]; sm2 += f[e] * f[e]; }
    #pragma unroll
    for (int o = 32; o > 0; o >>= 1) { sm += __shfl_xor(sm, o); sm2 += __shfl_xor(sm2, o); }
    const float inv = 1.0f / 512.0f;
    float mean = sm * inv;
    float var  = sm2 * inv - mean * mean;
    float rstd = rsqrtf(var + 1e-5f);

    float4 g0 = *(const float4*)(g + lane * 8);
    float4 g1 = *(const float4*)(g + lane * 8 + 4);
    float4 b0 = *(const float4*)(b + lane * 8);
    float4 b1 = *(const float4*)(b + lane * 8 + 4);
    float gg[8] = {g0.x, g0.y, g0.z, g0.w, g1.x, g1.y, g1.z, g1.w};
    float bb[8] = {b0.x, b0.y, b0.z, b0.w, b1.x, b1.y, b1.z, b1.w};
    u16x8 ov;
    #pragma unroll
    for (int e = 0; e < 8; ++e)
        ov[e] = f2bf((f[e] - mean) * rstd * gg[e] + bb[e]);
    *(u16x8*)(y + (size_t)row * 512 + lane * 8) = ov;
}

// -------- gate GEMM: 128x128 tile, dual-B, dbuf prefetch ------------------
// launch_bounds(256,2): the 2-block/CU PROVEN config (54.8us). Do NOT
// raise (round-10 spill: VGPR 84, FETCH/WRITE inflated, 54->95us).
// Chunk-32 fold (round-11 proven). Do NOT switch to chunk-16 fold
// (round-12: doubled scattered chunk-state stores -> 54.8->80us).
__global__ __launch_bounds__(256, 2) void gemm_gate(
    const u16* __restrict__ A, const u16* __restrict__ Bt0,
    const u16* __restrict__ Bt1, const float* __restrict__ bias0,
    const float* __restrict__ bias1, u32* __restrict__ cvb,
    float* __restrict__ chCp, float* __restrict__ chVp)
{
    constexpr int Kd = 512, Nd = 512;
    constexpr int BUF = 12288;
    __shared__ __align__(16) u16 smem[2 * BUF];   // 48 KiB

    int bx = blockIdx.x;
    bx = (bx & 7) * 128 + (bx >> 3);     // XCD-contiguous (1024%8==0)
    int m0 = (bx >> 2) * 128;
    int n0 = (bx & 3) * 128;
    int tid = threadIdx.x;
    int lane = tid & 63;
    int w = tid >> 6;
    int wm = w & 1, wn = w >> 1;
    int l16 = lane & 15;
    int quad = lane >> 4;

    f32x4 acc0[4][4] = {};
    f32x4 acc1[4][4] = {};

    int ch0 = tid, ch1 = tid + 256;
    int row0 = ch0 >> 2, row1 = ch1 >> 2;
    int g0 = (ch0 & 3) ^ ((ch0 >> 3) & 3);
    int g1 = (ch1 & 3) ^ ((ch1 >> 3) & 3);
    const u16* a0p  = A   + (size_t)(m0 + row0) * Kd + g0 * 8;
    const u16* a1p  = A   + (size_t)(m0 + row1) * Kd + g1 * 8;
    const u16* b00p = Bt0 + (size_t)(n0 + row0) * Kd + g0 * 8;
    const u16* b01p = Bt0 + (size_t)(n0 + row1) * Kd + g1 * 8;
    const u16* b10p = Bt1 + (size_t)(n0 + row0) * Kd + g0 * 8;
    const u16* b11p = Bt1 + (size_t)(n0 + row1) * Kd + g1 * 8;

#define STAGE(sl, kt) { \
    int k0_ = (kt) * 32; \
    u16* L_ = smem + (sl) * BUF; \
    gld16(a0p  + k0_, &L_[ch0 * 8]); \
    gld16(a1p  + k0_, &L_[ch1 * 8]); \
    gld16(b00p + k0_, &L_[4096 + ch0 * 8]); \
    gld16(b01p + k0_, &L_[4096 + ch1 * 8]); \
    gld16(b10p + k0_, &L_[8192 + ch0 * 8]); \
    gld16(b11p + k0_, &L_[8192 + ch1 * 8]); }

    STAGE(0, 0);
    __syncthreads();

    for (int kt = 0; kt < Kd / 32; ++kt) {
        int cur = kt & 1;
        if (kt < Kd / 32 - 1) STAGE(cur ^ 1, kt + 1);

        const u16* As  = smem + cur * BUF;
        const u16* Bs0 = As + 4096;
        const u16* Bs1 = As + 8192;
        bf16x8 af[4], bf0[4], bf1[4];
        #pragma unroll
        for (int i = 0; i < 4; ++i) {
            int ra = wm * 64 + i * 16 + l16;
            int rb = wn * 64 + i * 16 + l16;
            int ga = quad ^ ((ra >> 1) & 3);
            int gb = quad ^ ((rb >> 1) & 3);
            af[i]  = *(const bf16x8*)&As [ra * 32 + ga * 8];
            bf0[i] = *(const bf16x8*)&Bs0[rb * 32 + gb * 8];
            bf1[i] = *(const bf16x8*)&Bs1[rb * 32 + gb * 8];
        }
        #pragma unroll
        for (int i = 0; i < 4; ++i)
            #pragma unroll
            for (int j = 0; j < 4; ++j) {
                acc0[i][j] = __builtin_amdgcn_mfma_f32_16x16x32_bf16(af[i], bf0[j], acc0[i][j], 0, 0, 0);
                acc1[i][j] = __builtin_amdgcn_mfma_f32_16x16x32_bf16(af[i], bf1[j], acc1[i][j], 0, 0, 0);
            }
        __syncthreads();
    }
#undef STAGE

    #pragma unroll
    for (int p = 0; p < 2; ++p) {
        int grow = m0 + wm * 64 + p * 32;
        int bb_  = grow >> 13;
        int chgl = (grow & 8191) >> 5;
        #pragma unroll
        for (int j = 0; j < 4; ++j) {
            int col = n0 + wn * 64 + j * 16 + l16;
            float bk  = bias0[col];
            float bh2 = bias1[col];
            float Cs[2], Vs[2];
            #pragma unroll
            for (int ii = 0; ii < 2; ++ii) {
                int i = 2 * p + ii;
                float C = 1.f, V = 0.f;
                #pragma unroll
                for (int r = 0; r < 4; ++r) {
                    int row = m0 + wm * 64 + i * 16 + quad * 4 + r;
                    float kk = acc0[i][j][r] + bk;
                    float hh = acc1[i][j][r] + bh2;
                    float z = __builtin_amdgcn_rcpf(1.f + __expf(-kk));
                    float c = 1.f - z;
                    float gs = __builtin_amdgcn_rcpf(1.f + __expf(-hh));
                    float gg = (hh >= 0.f) ? (hh + 0.5f) : gs;
                    float v = z * gg;
                    cvb[(size_t)row * Nd + col] =
                        (u32)f2h(c) | ((u32)f2h(v) << 16);
                    C *= c;
                    V = fmaf(c, V, v);
                }
                Cs[ii] = C; Vs[ii] = V;
            }
            #pragma unroll
            for (int ii = 0; ii < 2; ++ii) {
                float C = Cs[ii], V = Vs[ii];
                float oc = __shfl_xor(C, 16), ov = __shfl_xor(V, 16);
                V = (quad & 1) ? fmaf(C, ov, V) : fmaf(oc, V, ov);
                C *= oc;
                oc = __shfl_xor(C, 32); ov = __shfl_xor(V, 32);
                V = (quad & 2) ? fmaf(C, ov, V) : fmaf(oc, V, ov);
                C *= oc;
                Cs[ii] = C; Vs[ii] = V;
            }
            float Cch = Cs[0] * Cs[1];
            float Vch = fmaf(Cs[1], Vs[0], Vs[1]);
            if (quad == 0) {
                int idx = chgl * 2048 + bb_ * 512 + col;
                chCp[idx] = Cch;
                chVp[idx] = Vch;
            }
        }
    }
}

// -------- FFN GEMM: 128x128 tile, single-B, dbuf prefetch -----------------
// launch_bounds(256,3): acc is only 64 VGPR here (~130 live total < 170
// budget at 3 blocks/CU) -> register-safe occupancy bump. LDS 32K x3 = 96K.
template <int MODE>
__global__ __launch_bounds__(256, 3) void gemm_bt(
    const u16* __restrict__ A, const u16* __restrict__ Bt0,
    const float* __restrict__ bias0, const float* __restrict__ resid,
    void* __restrict__ out0v)
{
    constexpr int Kd = 512, Nd = 512;
    constexpr int BUF = 8192;
    __shared__ __align__(16) u16 smem[2 * BUF];   // 32 KiB

    int bx = blockIdx.x;
    bx = (bx & 7) * 128 + (bx >> 3);
    int m0 = (bx >> 2) * 128;
    int n0 = (bx & 3) * 128;
    int tid = threadIdx.x;
    int lane = tid & 63;
    int w = tid >> 6;
    int wm = w & 1, wn = w >> 1;
    int l16 = lane & 15;
    int quad = lane >> 4;

    f32x4 acc0[4][4] = {};

    int ch0 = tid, ch1 = tid + 256;
    int row0 = ch0 >> 2, row1 = ch1 >> 2;
    int g0 = (ch0 & 3) ^ ((ch0 >> 3) & 3);
    int g1 = (ch1 & 3) ^ ((ch1 >> 3) & 3);
    const u16* a0p  = A   + (size_t)(m0 + row0) * Kd + g0 * 8;
    const u16* a1p  = A   + (size_t)(m0 + row1) * Kd + g1 * 8;
    const u16* b00p = Bt0 + (size_t)(n0 + row0) * Kd + g0 * 8;
    const u16* b01p = Bt0 + (size_t)(n0 + row1) * Kd + g1 * 8;

#define STAGE(sl, kt) { \
    int k0_ = (kt) * 32; \
    u16* L_ = smem + (sl) * BUF; \
    gld16(a0p  + k0_, &L_[ch0 * 8]); \
    gld16(a1p  + k0_, &L_[ch1 * 8]); \
    gld16(b00p + k0_, &L_[4096 + ch0 * 8]); \
    gld16(b01p + k0_, &L_[4096 + ch1 * 8]); }

    STAGE(0, 0);
    __syncthreads();

    for (int kt = 0; kt < Kd / 32; ++kt) {
        int cur = kt & 1;
        if (kt < Kd / 32 - 1) STAGE(cur ^ 1, kt + 1);

        const u16* As  = smem + cur * BUF;
        const u16* Bs0 = As + 4096;
        bf16x8 af[4], bf0[4];
        #pragma unroll
        for (int i = 0; i < 4; ++i) {
            int ra = wm * 64 + i * 16 + l16;
            int rb = wn * 64 + i * 16 + l16;
            int ga = quad ^ ((ra >> 1) & 3);
            int gb = quad ^ ((rb >> 1) & 3);
            af[i]  = *(const bf16x8*)&As [ra * 32 + ga * 8];
            bf0[i] = *(const bf16x8*)&Bs0[rb * 32 + gb * 8];
        }
        #pragma unroll
        for (int i = 0; i < 4; ++i)
            #pragma unroll
            for (int j = 0; j < 4; ++j)
                acc0[i][j] = __builtin_amdgcn_mfma_f32_16x16x32_bf16(af[i], bf0[j], acc0[i][j], 0, 0, 0);
        __syncthreads();
    }
#undef STAGE

    #pragma unroll
    for (int j = 0; j < 4; ++j) {
        int col = n0 + wn * 64 + j * 16 + l16;
        float b0 = bias0[col];
        #pragma unroll
        for (int i = 0; i < 4; ++i) {
            #pragma unroll
            for (int r = 0; r < 4; ++r) {
                int row = m0 + wm * 64 + i * 16 + quad * 4 + r;
                size_t off = (size_t)row * Nd + col;
                float v0 = acc0[i][j][r] + b0;
                if (MODE == 1) {
                    ((u16*)out0v)[off] = f2bf(fmaxf(v0, 0.f));
                } else {
                    ((float*)out0v)[off] = v0 + resid[off];
                }
            }
        }
    }
}

// -------- fused chunk-state scan (256 chunks of 32) ------------------------
__global__ __launch_bounds__(256) void scanB(
    const float* __restrict__ chC, const float* __restrict__ chV,
    float* __restrict__ hst)
{
    int bx = blockIdx.x;                 // 128 blocks
    int sc = bx >> 3;                    // 0..15
    int s  = (bx & 7) * 256 + threadIdx.x;   // 0..2047
    float h = 0.5f;
    int pre = sc * 16;
    #pragma unroll 8
    for (int c = 0; c < pre; ++c)
        h = fmaf(chC[c * 2048 + s], h, chV[c * 2048 + s]);
    #pragma unroll
    for (int i = 0; i < 16; ++i) {
        int ch = sc * 16 + i;
        hst[ch * 2048 + s] = h;
        h = fmaf(chC[ch * 2048 + s], h, chV[ch * 2048 + s]);
    }
}

// Pass C: replay 32-chunk from packed fp16 gates; x2 = x + h.
// ONE h per thread: 524288 threads = 2048 blocks = 8192 waves = 100%
// occupancy (the 2-h packing halved occupancy to 50% -- round-12 showed
// the occupancy restoration is worth ~18us). u32 gate load is 256B/wave,
// fully coalesced.
__global__ __launch_bounds__(256) void scanC(
    const u32* __restrict__ cv, const float* __restrict__ hst,
    const float* __restrict__ x, float* __restrict__ x2)
{
    int gid = blockIdx.x * 256 + threadIdx.x;   // 524288 threads
    int h = gid & 511;
    int rest = gid >> 9;
    int b = rest & 3;
    int ch = rest >> 2;                          // 0..255
    size_t base = ((size_t)(b * 8192 + ch * 32)) * 512 + h;
    float hc = hst[ch * 2048 + b * 512 + h];
    #pragma unroll 8
    for (int t = 0; t < 32; ++t) {
        size_t off = base + (size_t)t * 512;
        u32 g2 = cv[off];
        hc = fmaf(h2f((u16)(g2 & 0xffffu)), hc, h2f((u16)(g2 >> 16)));
        x2[off] = x[off] + hc;
    }
}

// ---------------------------------------------------------------------------
// All I/O fp32 (per reference). Internals bf16 (GEMM) / fp16 (gates).
// 7 dispatches: prep, gemm_gate, scanB, scanC, ln_k, gemm_bt<1>, gemm_bt<2>.
// ws layout (99.5 MiB):
//   wt  @ 0      : 2 MiB   (4 transposed bf16 weights)
//   a   @ 3.5 MiB: 32 MiB  bf16. LN1-out -> hst (2M) -> LN2-out.
//   cv  @ 35.5 M : 64 MiB  u32 packed (c,v) gates -> first 32 MiB reused
//     as FFN hidden after scanC.
// chC/chV (2 MiB each) alias d_out (dead until scanC; consumed by scanB
// before scanC overwrites d_out with x2).
// d_out holds x2 after scanC, then the final output (gemm_bt<2> reads
// resid[off] then writes out[off] from the same thread).
extern "C" void kernel_launch(void* const* d_in, const int* in_sizes, int n_in,
                              void* d_out, int out_size, void* d_ws, size_t ws_size,
                              hipStream_t stream)
{
    const float* x    = (const float*)d_in[0];
    const float* ln1g = (const float*)d_in[1];
    const float* ln1b = (const float*)d_in[2];
    const float* Wz   = (const float*)d_in[3];
    const float* bz   = (const float*)d_in[4];
    const float* Wh   = (const float*)d_in[5];
    const float* bh   = (const float*)d_in[6];
    const float* ln2g = (const float*)d_in[7];
    const float* ln2b = (const float*)d_in[8];
    const float* W1   = (const float*)d_in[9];
    const float* b1   = (const float*)d_in[10];
    const float* W2   = (const float*)d_in[11];
    const float* b2   = (const float*)d_in[12];
    float* out = (float*)d_out;

    char* ws = (char*)d_ws;
    constexpr size_t MB = 1024 * 1024;
    u16* Wzt = (u16*)(ws);
    u16* Wht = Wzt + 262144;
    u16* W1t = Wzt + 524288;
    u16* W2t = Wzt + 786432;
    u16* a   = (u16*)(ws + 3 * MB + 512 * 1024);   // LN1 out / LN2 out
    u32* cv  = (u32*)(ws + 35 * MB + 512 * 1024);  // packed gates (64 MiB)
    u16* hid = (u16*)(ws + 35 * MB + 512 * 1024);  // FFN hidden (reuses cv)
    float* hst = (float*)(ws + 3 * MB + 512 * 1024);
    float* chC = (float*)d_out;
    float* chV = chC + 524288;          // +2 MiB

    // a = bf16(LN1(x)) ; weights transposed to bf16
    prep<<<9216, 256, 0, stream>>>(x, ln1g, ln1b, a,
                                   Wz, Wh, W1, W2, Wzt, Wht, W1t, W2t);
    // cv = packed fp16 gates of (a@Wz+bz, a@Wh+bh); chC/chV = chunk states
    gemm_gate<<<1024, 256, 0, stream>>>(a, Wzt, Wht, bz, bh, cv, chC, chV);
    // hst = per-chunk start states (single fused pass)
    scanB<<<128, 256, 0, stream>>>(chC, chV, hst);
    // d_out = x + h  (fp32 residual stream; overwrites chC/chV - consumed)
    scanC<<<2048, 256, 0, stream>>>(cv, hst, x, out);
    // a = bf16(LN2(d_out))  (hst region dead)
    ln_k<<<8192, 256, 0, stream>>>(out, ln2g, ln2b, a, 32768);
    // hid = relu(a @ W1 + b1)  (bf16; cv region dead)
    gemm_bt<1><<<1024, 256, 0, stream>>>(a, W1t, b1, nullptr, hid);
    // d_out = hid @ W2 + b2 + d_out  (fp32)
    gemm_bt<2><<<1024, 256, 0, stream>>>(hid, W2t, b2, out, out);
}